// Round 1
// 967.240 us; speedup vs baseline: 1.1305x; 1.1305x over previous
//
#include <hip/hip_runtime.h>
#include <hip/hip_bf16.h>
#include <stdint.h>

// ---------------------------------------------------------------------------
// DeepseekV2 decoder layer, bf16 MFMA path, round 4.
// R3 post-mortem: all GEMMs sit on the m97-structure ceiling (~820 TF,
// MfmaUtil 37%, 44% of cycles in barrier drain: __syncthreads forces
// vmcnt(0) every BK step). Fix: T3+T4+T5 multi-phase K-loop with counted
// vmcnt at K-tile boundaries only, raw s_barrier, setprio around MFMA,
// 3/4-deep LDS buffer rotation (race-free by construction: stage target
// is never a readable buffer). 256x128 tiles -> grid 256 for q/o/down.
// ---------------------------------------------------------------------------

typedef __bf16 bf16;
typedef bf16 bf16x8 __attribute__((ext_vector_type(8)));
typedef bf16 bf16x4 __attribute__((ext_vector_type(4)));
typedef float f32x4 __attribute__((ext_vector_type(4)));

#define HID     2048
#define TOK     4096
#define INTER   10944
#define INTER_P 11008   // padded to multiple of 128; pad region is zeros

__device__ __forceinline__ void gload_lds16(const bf16* g, bf16* l) {
    __builtin_amdgcn_global_load_lds(
        (const __attribute__((address_space(1))) void*)g,
        (__attribute__((address_space(3))) void*)l, 16, 0, 0);
}

// Raw barrier (no implicit vmcnt(0) drain) — asm with memory clobber so the
// compiler cannot hoist LDS reads or stage-issues across it.
#define SBAR()      asm volatile("s_barrier" ::: "memory")
// K-tile boundary: counted vmcnt + barrier in ONE asm (nothing crosses).
#define WAIT_BAR(n) asm volatile("s_waitcnt vmcnt(" #n ")\n\ts_barrier" ::: "memory")
#define FMA16(d, a, b) d = __builtin_amdgcn_mfma_f32_16x16x32_bf16(a, b, d, 0, 0, 0)

// ---------------------------------------------------------------------------
// fp32 -> bf16 conversion with zero tail (row padding for Wg/Wu).
// ---------------------------------------------------------------------------
__global__ __launch_bounds__(256) void conv_pad(const float* __restrict__ src,
                                                bf16* __restrict__ dst,
                                                int n_src, int n_dst) {
    int i = (blockIdx.x * 256 + threadIdx.x) * 4;
    if (i >= n_dst) return;
    float4 v = make_float4(0.f, 0.f, 0.f, 0.f);
    if (i < n_src) v = *(const float4*)(src + i);
    bf16x4 o;
    o[0] = (bf16)v.x; o[1] = (bf16)v.y; o[2] = (bf16)v.z; o[3] = (bf16)v.w;
    *(bf16x4*)(dst + i) = o;
}

// Wd [2048,10944] -> [2048,11008], columns padded with zeros.
__global__ __launch_bounds__(256) void conv_wd(const float* __restrict__ src,
                                               bf16* __restrict__ dst) {
    int i = (blockIdx.x * 256 + threadIdx.x) * 4;
    if (i >= HID * INTER_P) return;
    int row = i / INTER_P;
    int col = i - row * INTER_P;
    float4 v = make_float4(0.f, 0.f, 0.f, 0.f);
    if (col < INTER)
        v = *(const float4*)(src + (size_t)row * INTER + col);
    bf16x4 o;
    o[0] = (bf16)v.x; o[1] = (bf16)v.y; o[2] = (bf16)v.z; o[3] = (bf16)v.w;
    *(bf16x4*)(dst + i) = o;
}

// ---------------------------------------------------------------------------
// RMSNorm: one block per row of 2048 fp32, emit bf16 * w.
// ---------------------------------------------------------------------------
__global__ __launch_bounds__(256) void rmsnorm_k(const float* __restrict__ x,
                                                 const float* __restrict__ w,
                                                 bf16* __restrict__ out) {
    const int row = blockIdx.x;
    const int tid = threadIdx.x;
    const float* xr = x + (size_t)row * HID + tid * 8;
    float4 v0 = *(const float4*)(xr);
    float4 v1 = *(const float4*)(xr + 4);
    float s = v0.x * v0.x + v0.y * v0.y + v0.z * v0.z + v0.w * v0.w +
              v1.x * v1.x + v1.y * v1.y + v1.z * v1.z + v1.w * v1.w;
    #pragma unroll
    for (int o = 32; o > 0; o >>= 1) s += __shfl_down(s, o);
    __shared__ float red[4];
    if ((tid & 63) == 0) red[tid >> 6] = s;
    __syncthreads();
    float tot = red[0] + red[1] + red[2] + red[3];
    float scale = rsqrtf(tot * (1.0f / (float)HID) + 1e-6f);
    float4 w0 = *(const float4*)(w + tid * 8);
    float4 w1 = *(const float4*)(w + tid * 8 + 4);
    bf16x8 o8;
    o8[0] = (bf16)(v0.x * scale * w0.x);
    o8[1] = (bf16)(v0.y * scale * w0.y);
    o8[2] = (bf16)(v0.z * scale * w0.z);
    o8[3] = (bf16)(v0.w * scale * w0.w);
    o8[4] = (bf16)(v1.x * scale * w1.x);
    o8[5] = (bf16)(v1.y * scale * w1.y);
    o8[6] = (bf16)(v1.z * scale * w1.z);
    o8[7] = (bf16)(v1.w * scale * w1.w);
    *(bf16x8*)(out + (size_t)row * HID + tid * 8) = o8;
}

// ---------------------------------------------------------------------------
// Pipelined GEMM C[M,N] = A[M,K] * W[N,K]^T.
// BM=256, BN=128, BK=64. 512 threads = 8 waves (4M x 2N), 64x64 per wave.
// 3 LDS buffers (48KB each, 144KB dynamic). While computing tile t from
// buf[t%3], stage tile t+2 into buf[(t+2)%3] (== buf[(t-1)%3], whose reads
// all retired before the last boundary barrier -> race-free).
// 4 phases per K-tile: zigzag C quadrants (0,0)->(0,1)->(1,1)->(1,0);
// A-quad + both W-quads carried in registers so ds_reads are {8,4,4,0}.
// Boundary: s_waitcnt vmcnt(6) (= 6 in-flight loads of tile t+2), s_barrier.
// ---------------------------------------------------------------------------
#define ABUF2 16384            // 256x64 elems
#define WBUF2 8192             // 128x64 elems
#define BUFE2 24576            // elems per buffer (48KB)

#define STGA(b, kk, i) gload_lds16(sA[i] + (kk), &lds[(b) * BUFE2 + (i) * 4096 + ldst])
#define STGW(b, kk, j) gload_lds16(sW[j] + (kk), &lds[(b) * BUFE2 + ABUF2 + (j) * 4096 + ldst])

template <int EPI>
__global__ __launch_bounds__(512, 2) void gemm_p2(const bf16* __restrict__ A,
                                                  const bf16* __restrict__ W,
                                                  const float* __restrict__ res,
                                                  void* __restrict__ out,
                                                  int N, int K) {
    extern __shared__ bf16 lds[];
    const int tid = threadIdx.x;
    const int rowBase = blockIdx.x * 256;   // M fastest: weight-panel locality
    const int colBase = blockIdx.y * 128;
    const int wave = tid >> 6, lane = tid & 63;
    const int wm = wave >> 1, wn = wave & 1;    // 4 M-waves x 2 N-waves
    const int fr = lane & 15, kq = lane >> 4;

    // staging: per 8KB load, thread t -> local row t>>3, lds chunk t&7;
    // source chunk pre-swizzled so linear LDS dest == swizzled layout.
    const int slr = tid >> 3;
    const int sc  = (tid & 7) ^ (slr & 7);
    const bf16* sA[4];
    #pragma unroll
    for (int i = 0; i < 4; ++i)
        sA[i] = A + (size_t)(rowBase + i * 64 + slr) * K + sc * 8;
    const bf16* sW[2];
    #pragma unroll
    for (int j = 0; j < 2; ++j)
        sW[j] = W + (size_t)(colBase + j * 64 + slr) * K + sc * 8;
    const int ldst = tid * 8;

    // fragment read offsets: row r, data chunk d=ks*4+kq stored at chunk d^(r&7)
    int aof[2][2][2], wof[2][2][2];
    #pragma unroll
    for (int q = 0; q < 2; ++q)
      #pragma unroll
      for (int ii = 0; ii < 2; ++ii) {
        const int ra = wm * 64 + q * 32 + ii * 16 + fr;
        const int rw = wn * 64 + q * 32 + ii * 16 + fr;
        #pragma unroll
        for (int ks = 0; ks < 2; ++ks) {
            aof[q][ii][ks] = ra * 64 + (((ks * 4 + kq) ^ (ra & 7)) * 8);
            wof[q][ii][ks] = ABUF2 + rw * 64 + (((ks * 4 + kq) ^ (rw & 7)) * 8);
        }
      }

    f32x4 acc[4][4] = {};
    bf16x8 af[2][2], w0[2][2], w1[2][2];
    const int NT = K >> 6;

    // prologue: tile 0 -> buf0, tile 1 -> buf1 (order A0..A3,W0,W1 per tile)
    STGA(0, 0, 0); STGA(0, 0, 1); STGA(0, 0, 2); STGA(0, 0, 3);
    STGW(0, 0, 0); STGW(0, 0, 1);
    STGA(1, 64, 0); STGA(1, 64, 1); STGA(1, 64, 2); STGA(1, 64, 3);
    STGW(1, 64, 0); STGW(1, 64, 1);
    WAIT_BAR(6);                 // tile 0 landed; tile 1's 6 still in flight

    int buf = 0, sbuf = 2;
    for (int t = 0; t < NT; ++t) {
        const int bb = buf * BUFE2;
        const bool st = (t + 2) < NT;
        const int kk = (t + 2) << 6;
        // ---- P0: quad (0,0)
        if (st) { STGA(sbuf, kk, 0); STGA(sbuf, kk, 1); }
        #pragma unroll
        for (int ii = 0; ii < 2; ++ii)
          #pragma unroll
          for (int ks = 0; ks < 2; ++ks) {
            af[ii][ks] = *(const bf16x8*)&lds[bb + aof[0][ii][ks]];
            w0[ii][ks] = *(const bf16x8*)&lds[bb + wof[0][ii][ks]];
          }
        SBAR();
        __builtin_amdgcn_s_setprio(1);
        #pragma unroll
        for (int ks = 0; ks < 2; ++ks)
          #pragma unroll
          for (int ii = 0; ii < 2; ++ii)
            #pragma unroll
            for (int jj = 0; jj < 2; ++jj)
                FMA16(acc[ii][jj], af[ii][ks], w0[jj][ks]);
        __builtin_amdgcn_s_setprio(0);
        SBAR();
        // ---- P1: quad (0,1)
        if (st) { STGA(sbuf, kk, 2); STGA(sbuf, kk, 3); }
        #pragma unroll
        for (int jj = 0; jj < 2; ++jj)
          #pragma unroll
          for (int ks = 0; ks < 2; ++ks)
            w1[jj][ks] = *(const bf16x8*)&lds[bb + wof[1][jj][ks]];
        SBAR();
        __builtin_amdgcn_s_setprio(1);
        #pragma unroll
        for (int ks = 0; ks < 2; ++ks)
          #pragma unroll
          for (int ii = 0; ii < 2; ++ii)
            #pragma unroll
            for (int jj = 0; jj < 2; ++jj)
                FMA16(acc[ii][2 + jj], af[ii][ks], w1[jj][ks]);
        __builtin_amdgcn_s_setprio(0);
        SBAR();
        // ---- P2: quad (1,1)
        if (st) STGW(sbuf, kk, 0);
        #pragma unroll
        for (int ii = 0; ii < 2; ++ii)
          #pragma unroll
          for (int ks = 0; ks < 2; ++ks)
            af[ii][ks] = *(const bf16x8*)&lds[bb + aof[1][ii][ks]];
        SBAR();
        __builtin_amdgcn_s_setprio(1);
        #pragma unroll
        for (int ks = 0; ks < 2; ++ks)
          #pragma unroll
          for (int ii = 0; ii < 2; ++ii)
            #pragma unroll
            for (int jj = 0; jj < 2; ++jj)
                FMA16(acc[2 + ii][2 + jj], af[ii][ks], w1[jj][ks]);
        __builtin_amdgcn_s_setprio(0);
        SBAR();
        // ---- P3: quad (1,0) (no ds_reads; af=quad1, w0 kept from P0)
        if (st) STGW(sbuf, kk, 1);
        SBAR();
        __builtin_amdgcn_s_setprio(1);
        #pragma unroll
        for (int ks = 0; ks < 2; ++ks)
          #pragma unroll
          for (int ii = 0; ii < 2; ++ii)
            #pragma unroll
            for (int jj = 0; jj < 2; ++jj)
                FMA16(acc[2 + ii][jj], af[ii][ks], w0[jj][ks]);
        __builtin_amdgcn_s_setprio(0);
        // boundary: tile t+1 must be landed; tile t+2's 6 loads may fly on
        if (st) WAIT_BAR(6); else WAIT_BAR(0);
        buf  = (buf  == 2) ? 0 : buf + 1;
        sbuf = (sbuf == 2) ? 0 : sbuf + 1;
    }
    // C/D layout: col = lane&15, row = (lane>>4)*4 + reg  [m89/m91]
    const int rq = lane >> 4, cn = lane & 15;
    #pragma unroll
    for (int mi = 0; mi < 4; ++mi)
      #pragma unroll
      for (int nj = 0; nj < 4; ++nj) {
        const int col = colBase + wn * 64 + nj * 16 + cn;
        #pragma unroll
        for (int r = 0; r < 4; ++r) {
            const int row = rowBase + wm * 64 + mi * 16 + rq * 4 + r;
            const size_t idx = (size_t)row * N + col;
            const float v = acc[mi][nj][r];
            if (EPI == 0) ((bf16*)out)[idx] = (bf16)v;
            else          ((float*)out)[idx] = res[idx] + v;
        }
      }
}

// ---------------------------------------------------------------------------
// Pipelined fused gate/up: gu = silu(A Wg^T) * (A Wu^T).
// BM=256, BN=128, BK=32 (3 staged matrices). 8 waves (4M x 2N), 64x64/wave.
// 4 LDS buffers (32KB each, 128KB dynamic), stage tile t+3 while computing t.
// 2 phases per K-tile (16 MFMA each); boundary vmcnt(8) = 2 tiles in flight.
// ---------------------------------------------------------------------------
#define ABUF3 8192             // 256x32 elems
#define GBUF3 4096             // 128x32 elems
#define BUFE3 16384            // elems per buffer (32KB)

__global__ __launch_bounds__(512, 2) void gemm_gup(const bf16* __restrict__ A,
                                                   const bf16* __restrict__ Wg,
                                                   const bf16* __restrict__ Wu,
                                                   bf16* __restrict__ out,
                                                   int N, int K) {
    extern __shared__ bf16 lds[];
    const int tid = threadIdx.x;
    const int rowBase = blockIdx.x * 256;
    const int colBase = blockIdx.y * 128;
    const int wave = tid >> 6, lane = tid & 63;
    const int wm = wave >> 1, wn = wave & 1;
    const int fr = lane & 15, kq = lane >> 4;

    // staging: per 8KB load, thread t -> local row t>>2, chunk t&3 (BK=32)
    const int slr = tid >> 2;
    const int sc  = (tid & 3) ^ ((slr >> 1) & 3);
    const bf16* sA0 = A  + (size_t)(rowBase +       slr) * K + sc * 8;
    const bf16* sA1 = A  + (size_t)(rowBase + 128 + slr) * K + sc * 8;
    const bf16* sG  = Wg + (size_t)(colBase +       slr) * K + sc * 8;
    const bf16* sU  = Wu + (size_t)(colBase +       slr) * K + sc * 8;
    const int ldst = tid * 8;

    int aof[4], gof[2][2];
    #pragma unroll
    for (int mi = 0; mi < 4; ++mi) {
        const int r = wm * 64 + mi * 16 + fr;
        aof[mi] = r * 32 + ((kq ^ ((r >> 1) & 3)) * 8);
    }
    #pragma unroll
    for (int q = 0; q < 2; ++q)
      #pragma unroll
      for (int jj = 0; jj < 2; ++jj) {
        const int r = wn * 64 + q * 32 + jj * 16 + fr;
        gof[q][jj] = ABUF3 + r * 32 + ((kq ^ ((r >> 1) & 3)) * 8);
      }

    f32x4 ag[4][4] = {}, au[4][4] = {};
    bf16x8 af[4], gq[2], uq[2];
    const int NT = K >> 5;

    // prologue: tiles 0..2 -> bufs 0..2 (order per tile: A0, A1, G, U)
    #pragma unroll
    for (int b = 0; b < 3; ++b) {
        gload_lds16(sA0 + b * 32, &lds[b * BUFE3 + ldst]);
        gload_lds16(sA1 + b * 32, &lds[b * BUFE3 + 4096 + ldst]);
        gload_lds16(sG  + b * 32, &lds[b * BUFE3 + ABUF3 + ldst]);
        gload_lds16(sU  + b * 32, &lds[b * BUFE3 + ABUF3 + GBUF3 + ldst]);
    }
    WAIT_BAR(8);                // tile 0 landed; tiles 1,2 (8 loads) in flight

    int buf = 0, sbuf = 3;
    for (int t = 0; t < NT; ++t) {
        const int bb = buf * BUFE3;
        const bool st = (t + 3) < NT;
        const int kk = (t + 3) << 5;
        // ---- P0: nj 0..1
        if (st) {
            gload_lds16(sA0 + kk, &lds[sbuf * BUFE3 + ldst]);
            gload_lds16(sA1 + kk, &lds[sbuf * BUFE3 + 4096 + ldst]);
        }
        #pragma unroll
        for (int mi = 0; mi < 4; ++mi)
            af[mi] = *(const bf16x8*)&lds[bb + aof[mi]];
        #pragma unroll
        for (int jj = 0; jj < 2; ++jj) {
            gq[jj] = *(const bf16x8*)&lds[bb + gof[0][jj]];
            uq[jj] = *(const bf16x8*)&lds[bb + gof[0][jj] + GBUF3];
        }
        SBAR();
        __builtin_amdgcn_s_setprio(1);
        #pragma unroll
        for (int mi = 0; mi < 4; ++mi)
          #pragma unroll
          for (int jj = 0; jj < 2; ++jj) {
            FMA16(ag[mi][jj], af[mi], gq[jj]);
            FMA16(au[mi][jj], af[mi], uq[jj]);
          }
        __builtin_amdgcn_s_setprio(0);
        SBAR();
        // ---- P1: nj 2..3
        if (st) {
            gload_lds16(sG + kk, &lds[sbuf * BUFE3 + ABUF3 + ldst]);
            gload_lds16(sU + kk, &lds[sbuf * BUFE3 + ABUF3 + GBUF3 + ldst]);
        }
        #pragma unroll
        for (int jj = 0; jj < 2; ++jj) {
            gq[jj] = *(const bf16x8*)&lds[bb + gof[1][jj]];
            uq[jj] = *(const bf16x8*)&lds[bb + gof[1][jj] + GBUF3];
        }
        SBAR();
        __builtin_amdgcn_s_setprio(1);
        #pragma unroll
        for (int mi = 0; mi < 4; ++mi)
          #pragma unroll
          for (int jj = 0; jj < 2; ++jj) {
            FMA16(ag[mi][2 + jj], af[mi], gq[jj]);
            FMA16(au[mi][2 + jj], af[mi], uq[jj]);
          }
        __builtin_amdgcn_s_setprio(0);
        // boundary: tile t+1 landed; up to 2 tiles (8 loads) stay in flight
        if (st)                WAIT_BAR(8);
        else if ((t + 2) < NT) WAIT_BAR(4);
        else                   WAIT_BAR(0);
        buf  = (buf + 1) & 3;
        sbuf = (sbuf + 1) & 3;
    }
    const int rq = lane >> 4, cn = lane & 15;
    #pragma unroll
    for (int mi = 0; mi < 4; ++mi)
      #pragma unroll
      for (int nj = 0; nj < 4; ++nj) {
        const int col = colBase + wn * 64 + nj * 16 + cn;
        #pragma unroll
        for (int r = 0; r < 4; ++r) {
            const int row = rowBase + wm * 64 + mi * 16 + rq * 4 + r;
            const float g = ag[mi][nj][r];
            const float u = au[mi][nj][r];
            const float sg = g / (1.0f + __expf(-g));  // silu
            out[(size_t)row * N + col] = (bf16)(sg * u);
        }
      }
}

// ---------------------------------------------------------------------------
extern "C" void kernel_launch(void* const* d_in, const int* in_sizes, int n_in,
                              void* d_out, int out_size, void* d_ws, size_t ws_size,
                              hipStream_t stream) {
    const float* x      = (const float*)d_in[0];
    const float* in_w   = (const float*)d_in[2];
    const float* post_w = (const float*)d_in[3];
    const float* Wq     = (const float*)d_in[4];
    const float* Wo     = (const float*)d_in[5];
    const float* Wg     = (const float*)d_in[6];
    const float* Wu     = (const float*)d_in[7];
    const float* Wd     = (const float*)d_in[8];

    // >64KB dynamic LDS needs the opt-in attribute (host-side, capture-safe).
    hipFuncSetAttribute(reinterpret_cast<const void*>(&gemm_p2<0>),
                        hipFuncAttributeMaxDynamicSharedMemorySize, 3 * BUFE2 * 2);
    hipFuncSetAttribute(reinterpret_cast<const void*>(&gemm_p2<1>),
                        hipFuncAttributeMaxDynamicSharedMemorySize, 3 * BUFE2 * 2);
    hipFuncSetAttribute(reinterpret_cast<const void*>(&gemm_gup),
                        hipFuncAttributeMaxDynamicSharedMemorySize, 4 * BUFE3 * 2);

    char* ws = (char*)d_ws;
    bf16*  X    = (bf16*)(ws + 0);           // 16.8MB: h_norm, later h_post
    bf16*  Yq   = (bf16*)(ws + 16777216);    // 16.8MB: q (bf16)
    float* hid  = (float*)(ws + 33554432);   // 33.6MB: hidden (fp32 residual)
    bf16*  gu   = (bf16*)(ws + 67108864);    // 90.2MB: silu(g)*u, padded
    bf16*  w0   = (bf16*)(ws + 157286400);   // 45.1MB: Wg bf16, later Wd bf16
    bf16*  w1   = (bf16*)(ws + 202375168);   // 45.1MB: Wu bf16
    bf16*  wsm  = (bf16*)(ws + 247463936);   // 8.4MB : Wq bf16, later Wo bf16

    const int nGU  = INTER_P * HID;
    const int nGUs = INTER * HID;
    const int nSq  = HID * HID;

    conv_pad<<<nGU / 4 / 256, 256, 0, stream>>>(Wg, w0, nGUs, nGU);
    conv_pad<<<nGU / 4 / 256, 256, 0, stream>>>(Wu, w1, nGUs, nGU);
    conv_pad<<<nSq / 4 / 256, 256, 0, stream>>>(Wq, wsm, nSq, nSq);

    rmsnorm_k<<<TOK, 256, 0, stream>>>(x, in_w, X);
    // q = h_norm @ Wq^T   (grid: x = M-tiles of 256, y = N-panels of 128)
    gemm_p2<0><<<dim3(TOK / 256, HID / 128), 512, 3 * BUFE2 * 2, stream>>>(
        X, wsm, nullptr, Yq, HID, HID);
    conv_pad<<<nSq / 4 / 256, 256, 0, stream>>>(Wo, wsm, nSq, nSq);
    // hidden = x + q @ Wo^T
    gemm_p2<1><<<dim3(TOK / 256, HID / 128), 512, 3 * BUFE2 * 2, stream>>>(
        Yq, wsm, x, hid, HID, HID);
    rmsnorm_k<<<TOK, 256, 0, stream>>>(hid, post_w, X);
    // gu = silu(h_post @ Wg^T) * (h_post @ Wu^T)
    gemm_gup<<<dim3(TOK / 256, INTER_P / 128), 512, 4 * BUFE3 * 2, stream>>>(
        X, w0, w1, gu, INTER_P, HID);
    conv_wd<<<nGU / 4 / 256, 256, 0, stream>>>(Wd, w0);
    // out = hidden + gu @ Wd^T
    gemm_p2<1><<<dim3(TOK / 256, HID / 128), 512, 3 * BUFE2 * 2, stream>>>(
        gu, w0, hid, (float*)d_out, HID, INTER_P);
}